// Round 16
// baseline (282.120 us; speedup 1.0000x reference)
//
#include <hip/hip_runtime.h>
#include <cstdint>

typedef unsigned short UST;
typedef __bf16 v8bf __attribute__((ext_vector_type(8)));
typedef float v4f __attribute__((ext_vector_type(4)));

static __device__ __forceinline__ UST f2b(float f) {
  union { float f; uint32_t u; } c; c.f = f;
  uint32_t u = c.u;
  u += 0x7fffu + ((u >> 16) & 1u);   // RNE
  return (UST)(u >> 16);
}
static __device__ __forceinline__ float b2f(UST h) {
  union { uint32_t u; float f; } c; c.u = ((uint32_t)h) << 16;
  return c.f;
}
static __device__ __forceinline__ uint32_t cvtpk(float lo, float hi) {
  uint32_t r;
  asm("v_cvt_pk_bf16_f32 %0, %1, %2" : "=v"(r) : "v"(lo), "v"(hi));
  return r;
}
static __device__ __forceinline__ float fexp2(float x) {  // 2^x
  float r;
  asm("v_exp_f32 %0, %1" : "=v"(r) : "v"(x));
  return r;
}
template <int N>
static __device__ __forceinline__ void wait_vm() {
  asm volatile("s_waitcnt vmcnt(%0)" :: "i"(N));
}

// async global->LDS, 16B per lane; global src per-lane, LDS dst wave-uniform+lane*16
static __device__ __forceinline__ void gl_lds16(const UST* g, UST* l) {
  __builtin_amdgcn_global_load_lds(
      (const __attribute__((address_space(1))) void*)g,
      (__attribute__((address_space(3))) void*)l, 16, 0, 0);
}

// ======== fused prologue: x cast (blocks 0..4095) + 4x W transpose+cast ========
__global__ __launch_bounds__(256) void k_prologue(const float* __restrict__ x,
                                                  const float* __restrict__ Wq,
                                                  const float* __restrict__ Wk,
                                                  const float* __restrict__ Wv,
                                                  const float* __restrict__ Wo,
                                                  UST* __restrict__ xb,
                                                  UST* __restrict__ wcat,
                                                  UST* __restrict__ wot) {
  int bx = blockIdx.x;
  int tx = threadIdx.x, ty = threadIdx.y;  // 32 x 8
  if (bx < 4096) {  // ---- cast x f32 -> bf16, 8 elems/thread ----
    int tid = ty * 32 + tx;
    size_t i = (size_t)bx * 256 + tid;
    const float4* s4 = reinterpret_cast<const float4*>(x) + 2 * i;
    float4 a = s4[0], b = s4[1];
    union { UST s[8]; uint4 v; } r;
    r.s[0] = f2b(a.x); r.s[1] = f2b(a.y); r.s[2] = f2b(a.z); r.s[3] = f2b(a.w);
    r.s[4] = f2b(b.x); r.s[5] = f2b(b.y); r.s[6] = f2b(b.z); r.s[7] = f2b(b.w);
    reinterpret_cast<uint4*>(xb)[i] = r.v;
    return;
  }
  // ---- transpose+cast: W [2048][N] f32 -> dst [N][2048] bf16 ----
  int u = bx - 4096;
  int ky = u & 63, wsel = u >> 6;
  const float* W; UST* dst; int N; int nb;
  if (wsel < 64)       { W = Wq; dst = wcat;                          N = 2048; nb = wsel; }
  else if (wsel < 80)  { W = Wk; dst = wcat + (size_t)2048 * 2048;    N = 512;  nb = wsel - 64; }
  else if (wsel < 96)  { W = Wv; dst = wcat + (size_t)2560 * 2048;    N = 512;  nb = wsel - 80; }
  else                 { W = Wo; dst = wot;                           N = 2048; nb = wsel - 96; }
  constexpr int K = 2048;
  __shared__ float tile[32][33];
  int nt = nb * 32, kt = ky * 32;
#pragma unroll
  for (int r = 0; r < 4; ++r)
    tile[ty + r * 8][tx] = W[(size_t)(kt + ty + r * 8) * N + nt + tx];
  __syncthreads();
#pragma unroll
  for (int r = 0; r < 4; ++r)
    dst[(size_t)(nt + ty + r * 8) * K + kt + tx] = f2b(tile[tx][ty + r * 8]);
}

// ====== r12 GEMM: slice-granular depth-3 pipeline + r11 swizzle (unchanged) ======
template <int BM, int BN, int WM, int WN, int NMH, int EPI>
__global__ __launch_bounds__(512, 2) void k_gemm2(const UST* __restrict__ A,
                                                  const UST* __restrict__ Bt,
                                                  void* __restrict__ Cv,
                                                  const float* __restrict__ bias,
                                                  int M, int N, int K, int ntn) {
  constexpr int WMR = BM / WM, WNR = BN / WN;
  constexpr int MF = WMR / 16, NF = WNR / 16, MH = MF / NMH;
  constexpr int CA = BM / 128;
  constexpr int CBF = BN / 128;
  constexpr int BREM = (BN % 128) / 64;
  constexpr int AELEMS = 4 * BM * 32;
  __shared__ __align__(16) UST lds[AELEMS + 4 * BN * 32];

  int tid = threadIdx.x, w = tid >> 6, lane = tid & 63;
  int lr = lane & 15, lg = lane >> 4;
  int wm = w / WN, wn = w % WN;

  int q = (int)gridDim.x >> 3;
  int bid = (int)blockIdx.x;
  int swz = (bid & 7) * q + (bid >> 3);
  int mBlk = (swz / ntn) * BM, nBlk = (swz % ntn) * BN;

  v4f acc[MF][NF];
#pragma unroll
  for (int i = 0; i < MF; ++i)
#pragma unroll
    for (int j = 0; j < NF; ++j) acc[i][j] = (v4f){0.f, 0.f, 0.f, 0.f};

  int srow = tid >> 2;
  int scol = ((tid & 3) ^ ((tid >> 3) & 3)) * 8;
  const UST* Abase = A + (size_t)(mBlk + srow) * K + scol;
  const UST* Bbase = Bt + (size_t)(nBlk + srow) * K + scol;
  int ldsW = w * 512;

  auto stageSlice = [&](int v) {
    int reg = v & 3;
    int koff = (v >> 1) * 64 + (v & 1) * 32;
#pragma unroll
    for (int i = 0; i < CA; ++i)
      gl_lds16(Abase + (size_t)(i * 128) * K + koff,
               &lds[reg * BM * 32 + i * 4096 + ldsW]);
#pragma unroll
    for (int i = 0; i < CBF; ++i)
      gl_lds16(Bbase + (size_t)(i * 128) * K + koff,
               &lds[AELEMS + reg * BN * 32 + i * 4096 + ldsW]);
    if constexpr (BREM) {
      if (w < 4)
        gl_lds16(Bbase + (size_t)(CBF * 128) * K + koff,
                 &lds[AELEMS + reg * BN * 32 + CBF * 4096 + ldsW]);
    }
  };
  auto wait2 = [&]() {
    if constexpr (BREM) {
      if (w < 4) wait_vm<2 * (CA + CBF + 1)>();
      else       wait_vm<2 * (CA + CBF)>();
    } else {
      wait_vm<2 * (CA + CBF)>();
    }
  };
  int rslot = ((lg ^ ((lr >> 1) & 3)) * 8);
  auto ldA = [&](int reg, int f) -> v8bf {
    int row = wm * WMR + f * 16 + lr;
    return *(const v8bf*)&lds[(reg * BM + row) * 32 + rslot];
  };
  auto ldB = [&](int reg, int nf) -> v8bf {
    int row = wn * WNR + nf * 16 + lr;
    return *(const v8bf*)&lds[AELEMS + (reg * BN + row) * 32 + rslot];
  };

  int U = K >> 5;
  stageSlice(0); stageSlice(1); stageSlice(2);
  wait2();
  __builtin_amdgcn_s_barrier();

  auto slice = [&](int u, bool issue, int wkind) {
    int reg = u & 3;
    v8bf bfr[NF];
#pragma unroll
    for (int mh = 0; mh < NMH; ++mh) {
      v8bf afr[MH];
      if (mh == 0) {
#pragma unroll
        for (int nf = 0; nf < NF; ++nf) bfr[nf] = ldB(reg, nf);
      }
#pragma unroll
      for (int f = 0; f < MH; ++f) afr[f] = ldA(reg, mh * MH + f);
      if (mh == 0 && issue) stageSlice(u + 3);
      if (mh == NMH - 1) {
        if (wkind == 1) wait2();
        else if (wkind == 2) wait_vm<0>();
      }
      __builtin_amdgcn_s_barrier();
      __builtin_amdgcn_s_setprio(1);
#pragma unroll
      for (int f = 0; f < MH; ++f)
#pragma unroll
        for (int nf = 0; nf < NF; ++nf)
          acc[mh * MH + f][nf] = __builtin_amdgcn_mfma_f32_16x16x32_bf16(
              afr[f], bfr[nf], acc[mh * MH + f][nf], 0, 0, 0);
      __builtin_amdgcn_s_setprio(0);
      __builtin_amdgcn_s_barrier();
    }
  };

  for (int u = 0; u < U - 3; ++u) slice(u, true, 1);
  slice(U - 3, false, 2);
  slice(U - 2, false, 0);
  slice(U - 1, false, 0);

  int row0 = mBlk + wm * WMR + lg * 4;
  int col0 = nBlk + wn * WNR + lr;
#pragma unroll
  for (int fm = 0; fm < MF; ++fm)
#pragma unroll
    for (int nf = 0; nf < NF; ++nf)
#pragma unroll
      for (int r = 0; r < 4; ++r) {
        int row = row0 + fm * 16 + r;
        int col = col0 + nf * 16;
        if constexpr (EPI == 0) {
          ((UST*)Cv)[(size_t)row * N + col] = f2b(acc[fm][nf][r]);
        } else {
          ((float*)Cv)[(size_t)row * N + col] = acc[fm][nf][r] + bias[col];
        }
      }
}

// ======== fused RoPE (blocks 0..2559) + V-transpose (blocks 2560..3071) ========
__global__ __launch_bounds__(256) void k_ropevt(const UST* __restrict__ qkv,
                                                const float* __restrict__ cosT,
                                                const float* __restrict__ sinT,
                                                UST* __restrict__ qh,
                                                UST* __restrict__ kh,
                                                UST* __restrict__ vt) {
  int v = blockIdx.x;
  if (v < 2560) {  // ---- RoPE, 8 d-elems/thread (q pre-scaled 1/8) ----
    int idx = v * 256 + threadIdx.x;
    int q4 = idx & 3;
    int hh = (idx >> 2) % 40;
    int row = idx / 160;            // b*2048 + l
    int l = row & 2047, b = row >> 11;
    int d0 = q4 * 8;
    int col = (hh < 32) ? hh * 64 : 2048 + (hh - 32) * 64;
    const UST* sp = qkv + (size_t)row * 3072 + col + d0;
    union { uint4 v4u; UST u[8]; } t1, t2, o1, o2;
    t1.v4u = *(const uint4*)sp;
    t2.v4u = *(const uint4*)(sp + 32);
    const float4* cp = (const float4*)&cosT[l * 64 + d0];
    const float4* sn = (const float4*)&sinT[l * 64 + d0];
    float4 ca = cp[0], cb = cp[1], sa = sn[0], sb = sn[1];
    float cc[8] = {ca.x, ca.y, ca.z, ca.w, cb.x, cb.y, cb.z, cb.w};
    float ss[8] = {sa.x, sa.y, sa.z, sa.w, sb.x, sb.y, sb.z, sb.w};
    float scale = (hh < 32) ? 0.125f : 1.f;
#pragma unroll
    for (int j = 0; j < 8; ++j) {
      float a = b2f(t1.u[j]), bb = b2f(t2.u[j]);
      o1.u[j] = f2b((a * cc[j] - bb * ss[j]) * scale);
      o2.u[j] = f2b((bb * cc[j] + a * ss[j]) * scale);
    }
    UST* dst = (hh < 32)
        ? qh + (((size_t)b * 32 + hh) * 2048 + l) * 64 + d0
        : kh + (((size_t)b * 8 + (hh - 32)) * 2048 + l) * 64 + d0;
    *(uint4*)dst = o1.v4u;
    *(uint4*)(dst + 32) = o2.v4u;
    return;
  }
  // ---- V transpose: qkv v-slice -> vt [B][8][64][L] ----
  __shared__ __align__(16) UST tl[64][72];
  int u2 = v - 2560;
  int lt = u2 & 31, bg = u2 >> 5;
  int b = bg >> 3, g = bg & 7;
  int t = threadIdx.x;
  int li = t >> 2, d0 = (t & 3) * 16;
  const UST* src = qkv + (size_t)(b * 2048 + lt * 64 + li) * 3072 + 2560 + g * 64 + d0;
  *(uint4*)&tl[li][d0] = *(const uint4*)src;
  *(uint4*)&tl[li][d0 + 8] = *(const uint4*)(src + 8);
  __syncthreads();
  int d = t >> 2, l0 = (t & 3) * 16;
  union { UST u[8]; uint4 v4u; } r0, r1;
#pragma unroll
  for (int e = 0; e < 8; ++e) r0.u[e] = tl[l0 + e][d];
#pragma unroll
  for (int e = 0; e < 8; ++e) r1.u[e] = tl[l0 + 8 + e][d];
  UST* dstp = vt + (size_t)((b * 8 + g) * 64 + d) * 2048 + (size_t)lt * 64 + l0;
  *(uint4*)dstp = r0.v4u;
  *(uint4*)(dstp + 8) = r1.v4u;
}

// ---------------- causal flash attention v5: 4 waves x 32 q-rows ----------------
// r13 kernel (correctness-verified) with two deltas: (1) launch_bounds(256,1)
// — loosest VGPR cap so the ~165-reg body allocates without spill (r13 died on
// spill under (256,2)); (2) p_s chunked to [4][32][72] (PV in two 64-kpos
// passes, wave-private reuse, r6/r7-verified pattern) -> LDS 54272 B.
// Grid (8,32,2) balanced pairs, KVBLK=128, one kf/vb LDS read feeds 2 MFMAs.
__global__ __launch_bounds__(256, 1) void k_attn(const UST* __restrict__ qh,
                                                 const UST* __restrict__ kh,
                                                 const UST* __restrict__ vt,
                                                 UST* __restrict__ outp) {
  __shared__ __align__(16) UST k_s[128 * 72];      // K tile [kpos][64], pad->72
  __shared__ __align__(16) UST v_s[64 * 136];      // V^T tile [d][128], pad->136
  __shared__ __align__(16) UST p_s[4][32 * 72];    // per-wave P chunk [32 q][64 k]
  int bx = blockIdx.x, h = blockIdx.y, b = blockIdx.z;
  int g = h >> 2;
  int tid = threadIdx.x, w = tid >> 6, lane = tid & 63;
  int lr = lane & 15, lg = lane >> 4;

  // staging (256 threads): K thread t -> row t>>1, half (t&1); V row t>>2, quarter (t&3)
  int ksr = tid >> 1, ksc = (tid & 1) * 32;
  int vsr = tid >> 2, vsc = (tid & 3) * 32;
  const UST* kbase = kh + ((size_t)(b * 8 + g) * 2048 + ksr) * 64 + ksc;
  const UST* vbase = vt + ((size_t)(b * 8 + g) * 64 + vsr) * 2048 + vsc;
  UST* kdst = &k_s[ksr * 72 + ksc];
  UST* vdst = &v_s[vsr * 136 + vsc];

  for (int half = 0; half < 2; ++half) {
    int qt = half ? (15 - bx) : bx;
    int qbase = qt * 128 + w * 32;

    v8bf qf[2][2];
#pragma unroll
    for (int mt = 0; mt < 2; ++mt) {
      const UST* qp = qh + ((size_t)(b * 32 + h) * 2048 + qbase + mt * 16 + lr) * 64 + lg * 8;
      qf[mt][0] = *(const v8bf*)qp;
      qf[mt][1] = *(const v8bf*)(qp + 32);
    }

    float m[2] = {-1e30f, -1e30f}, ls[2] = {0.f, 0.f};
    v4f o[2][4];
#pragma unroll
    for (int mt = 0; mt < 2; ++mt)
#pragma unroll
      for (int dt = 0; dt < 4; ++dt) o[mt][dt] = (v4f){0.f, 0.f, 0.f, 0.f};

    __syncthreads();  // prior half's tile reads complete
    uint4 pk[4], pv[4];
#pragma unroll
    for (int e = 0; e < 4; ++e) {
      pk[e] = *(const uint4*)(kbase + e * 8);
      pv[e] = *(const uint4*)(vbase + e * 8);
    }
#pragma unroll
    for (int e = 0; e < 4; ++e) {
      *(uint4*)(kdst + e * 8) = pk[e];
      *(uint4*)(vdst + e * 8) = pv[e];
    }

    for (int j = 0; j <= qt; ++j) {
      __syncthreads();  // staged tile visible
      bool pref = (j < qt);
      if (pref) {  // register-prefetch next tile; hides under compute
        const UST* kg = kbase + (size_t)(j + 1) * 8192;
        const UST* vg = vbase + (j + 1) * 128;
#pragma unroll
        for (int e = 0; e < 4; ++e) {
          pk[e] = *(const uint4*)(kg + e * 8);
          pv[e] = *(const uint4*)(vg + e * 8);
        }
      }

      // S^T = K * Q^T : 32 MFMAs from 16 kf reads (kf shared across mt)
      v4f st[2][8];
      __builtin_amdgcn_s_setprio(1);
#pragma unroll
      for (int kt = 0; kt < 8; ++kt) {
        const UST* kr = &k_s[(kt * 16 + lr) * 72 + lg * 8];
        v8bf kf0 = *(const v8bf*)kr;
        v8bf kf1 = *(const v8bf*)(kr + 32);
#pragma unroll
        for (int mt = 0; mt < 2; ++mt) {
          v4f z = (v4f){0.f, 0.f, 0.f, 0.f};
          z = __builtin_amdgcn_mfma_f32_16x16x32_bf16(kf0, qf[mt][0], z, 0, 0, 0);
          z = __builtin_amdgcn_mfma_f32_16x16x32_bf16(kf1, qf[mt][1], z, 0, 0, 0);
          st[mt][kt] = z;
        }
      }
      __builtin_amdgcn_s_setprio(0);
      if (j == qt) {  // diagonal: causal mask
#pragma unroll
        for (int mt = 0; mt < 2; ++mt) {
          int qg = qbase + mt * 16 + lr;
#pragma unroll
          for (int kt = 0; kt < 8; ++kt)
#pragma unroll
            for (int r = 0; r < 4; ++r) {
              int kp = j * 128 + kt * 16 + 4 * lg + r;
              if (kp > qg) st[mt][kt][r] = -1e30f;
            }
        }
      }

      constexpr float LOG2E = 1.44269504f;
      float mlog[2], rs[2] = {0.f, 0.f};
#pragma unroll
      for (int mt = 0; mt < 2; ++mt) {  // max + defer-rescale per mt
        float t0 = fmaxf(fmaxf(st[mt][0][0], st[mt][0][1]), fmaxf(st[mt][0][2], st[mt][0][3]));
        float t1 = fmaxf(fmaxf(st[mt][1][0], st[mt][1][1]), fmaxf(st[mt][1][2], st[mt][1][3]));
        float t2 = fmaxf(fmaxf(st[mt][2][0], st[mt][2][1]), fmaxf(st[mt][2][2], st[mt][2][3]));
        float t3 = fmaxf(fmaxf(st[mt][3][0], st[mt][3][1]), fmaxf(st[mt][3][2], st[mt][3][3]));
        float t4 = fmaxf(fmaxf(st[mt][4][0], st[mt][4][1]), fmaxf(st[mt][4][2], st[mt][4][3]));
        float t5 = fmaxf(fmaxf(st[mt][5][0], st[mt][5][1]), fmaxf(st[mt][5][2], st[mt][5][3]));
        float t6 = fmaxf(fmaxf(st[mt][6][0], st[mt][6][1]), fmaxf(st[mt][6][2], st[mt][6][3]));
        float t7 = fmaxf(fmaxf(st[mt][7][0], st[mt][7][1]), fmaxf(st[mt][7][2], st[mt][7][3]));
        float mx = fmaxf(fmaxf(fmaxf(t0, t1), fmaxf(t2, t3)),
                         fmaxf(fmaxf(t4, t5), fmaxf(t6, t7)));
        mx = fmaxf(mx, __shfl_xor(mx, 16));
        mx = fmaxf(mx, __shfl_xor(mx, 32));

        if (!__all(mx <= m[mt] + 8.f)) {   // defer-max (T13)
          float mn = fmaxf(m[mt], mx);
          float al = __expf(m[mt] - mn);
          m[mt] = mn;
          ls[mt] *= al;
#pragma unroll
          for (int r = 0; r < 4; ++r) {
            float ar = __shfl(al, 4 * lg + r);
            o[mt][0][r] *= ar; o[mt][1][r] *= ar;
            o[mt][2][r] *= ar; o[mt][3][r] *= ar;
          }
        }
        mlog[mt] = m[mt] * LOG2E;
      }

      // exp + P->LDS + PV in two 64-kpos chunks through the reused p_s buffer
#pragma unroll
      for (int c = 0; c < 2; ++c) {
#pragma unroll
        for (int mt = 0; mt < 2; ++mt) {
          UST* pw = &p_s[w][(mt * 16 + lr) * 72 + 4 * lg];
#pragma unroll
          for (int k2 = 0; k2 < 4; ++k2) {
            int kt = c * 4 + k2;
            float p0 = fexp2(__builtin_fmaf(st[mt][kt][0], LOG2E, -mlog[mt]));
            float p1 = fexp2(__builtin_fmaf(st[mt][kt][1], LOG2E, -mlog[mt]));
            float p2 = fexp2(__builtin_fmaf(st[mt][kt][2], LOG2E, -mlog[mt]));
            float p3 = fexp2(__builtin_fmaf(st[mt][kt][3], LOG2E, -mlog[mt]));
            rs[mt] += (p0 + p1) + (p2 + p3);
            uint2 q2;
            q2.x = cvtpk(p0, p1);
            q2.y = cvtpk(p2, p3);
            *(uint2*)(pw + k2 * 16) = q2;
          }
        }
        // PV chunk c: 16 MFMAs from 4 pa + 8 vb reads (vb shared across mt)
        __builtin_amdgcn_s_setprio(1);
#pragma unroll
        for (int kkl = 0; kkl < 2; ++kkl) {
          v8bf pa0 = *(const v8bf*)&p_s[w][lr * 72 + kkl * 32 + lg * 8];
          v8bf pa1 = *(const v8bf*)&p_s[w][(16 + lr) * 72 + kkl * 32 + lg * 8];
#pragma unroll
          for (int dt = 0; dt < 4; ++dt) {
            v8bf vb = *(const v8bf*)&v_s[(dt * 16 + lr) * 136 + (c * 2 + kkl) * 32 + lg * 8];
            o[0][dt] = __builtin_amdgcn_mfma_f32_16x16x32_bf16(pa0, vb, o[0][dt], 0, 0, 0);
            o[1][dt] = __builtin_amdgcn_mfma_f32_16x16x32_bf16(pa1, vb, o[1][dt], 0, 0, 0);
          }
        }
        __builtin_amdgcn_s_setprio(0);
      }

      // row-sum reduce AFTER PV (off PV's dependency path)
#pragma unroll
      for (int mt = 0; mt < 2; ++mt) {
        rs[mt] += __shfl_xor(rs[mt], 16);
        rs[mt] += __shfl_xor(rs[mt], 32);
        ls[mt] += rs[mt];
      }

      __syncthreads();  // tile reads done
      if (pref) {
#pragma unroll
        for (int e = 0; e < 4; ++e) {
          *(uint4*)(kdst + e * 8) = pk[e];
          *(uint4*)(vdst + e * 8) = pv[e];
        }
      }
    }

    // epilogue: normalize and store O as [B*L][H*64] bf16
#pragma unroll
    for (int mt = 0; mt < 2; ++mt) {
      float iv = 1.f / ls[mt];
#pragma unroll
      for (int r = 0; r < 4; ++r) {
        float ivr = __shfl(iv, 4 * lg + r);
        size_t rowb = ((size_t)b * 2048 + qbase + mt * 16 + 4 * lg + r) * 2048 + h * 64 + lr;
#pragma unroll
        for (int dt = 0; dt < 4; ++dt)
          outp[rowb + dt * 16] = f2b(o[mt][dt][r] * ivr);
      }
    }
  }
}

// ---------------- launch ----------------
extern "C" void kernel_launch(void* const* d_in, const int* in_sizes, int n_in,
                              void* d_out, int out_size, void* d_ws, size_t ws_size,
                              hipStream_t stream) {
  const float* x    = (const float*)d_in[0];
  const float* cosT = (const float*)d_in[2];
  const float* sinT = (const float*)d_in[3];
  const float* Wq   = (const float*)d_in[4];
  const float* Wk   = (const float*)d_in[5];
  const float* Wv   = (const float*)d_in[6];
  const float* Wo   = (const float*)d_in[7];
  const float* bo   = (const float*)d_in[8];
  float* out = (float*)d_out;

  char* ws = (char*)d_ws;
  UST* xb   = (UST*)(ws);                       // 16777216 B
  UST* wcat = (UST*)(ws + 16777216);            // 12582912 B
  UST* wot  = (UST*)(ws + 29360128);            //  8388608 B
  UST* qkv  = (UST*)(ws + 37748736);            // 25165824 B
  UST* qhp  = (UST*)(ws + 62914560);            // 16777216 B
  UST* khp  = (UST*)(ws + 79691776);            //  4194304 B
  UST* vtp  = (UST*)(ws + 83886080);            //  4194304 B
  UST* attn_o = xb;  // xb dead after QKV GEMM

  // fused prologue: cast (4096) + 4 transposes (160*64 = 10240) = 14336 blocks
  k_prologue<<<14336, dim3(32, 8), 0, stream>>>(x, Wq, Wk, Wv, Wo, xb, wcat, wot);

  // QKV: 256x192 tiles -> 256 blocks (perfect fill); NMH=1
  k_gemm2<256, 192, 2, 4, 1, 0><<<256, 512, 0, stream>>>(xb, wcat, qkv, nullptr,
                                                         4096, 3072, 2048, 16);
  // fused RoPE (2560) + V transpose (512) = 3072 blocks
  k_ropevt<<<3072, 256, 0, stream>>>(qkv, cosT, sinT, qhp, khp, vtp);

  k_attn<<<dim3(8, 32, 2), 256, 0, stream>>>(qhp, khp, vtp, attn_o);
  // out: 256x128 tiles -> 256 blocks (full fill), NMH=1
  k_gemm2<256, 128, 4, 2, 1, 1><<<256, 512, 0, stream>>>(attn_o, wot, out, bo,
                                                         4096, 2048, 2048, 16);
}

// Round 17
// 191.591 us; speedup vs baseline: 1.4725x; 1.4725x over previous
//
#include <hip/hip_runtime.h>
#include <cstdint>

typedef unsigned short UST;
typedef __bf16 v8bf __attribute__((ext_vector_type(8)));
typedef float v4f __attribute__((ext_vector_type(4)));

static __device__ __forceinline__ UST f2b(float f) {
  union { float f; uint32_t u; } c; c.f = f;
  uint32_t u = c.u;
  u += 0x7fffu + ((u >> 16) & 1u);   // RNE
  return (UST)(u >> 16);
}
static __device__ __forceinline__ float b2f(UST h) {
  union { uint32_t u; float f; } c; c.u = ((uint32_t)h) << 16;
  return c.f;
}
static __device__ __forceinline__ uint32_t cvtpk(float lo, float hi) {
  uint32_t r;
  asm("v_cvt_pk_bf16_f32 %0, %1, %2" : "=v"(r) : "v"(lo), "v"(hi));
  return r;
}
static __device__ __forceinline__ float fexp2(float x) {  // 2^x
  float r;
  asm("v_exp_f32 %0, %1" : "=v"(r) : "v"(x));
  return r;
}
template <int N>
static __device__ __forceinline__ void wait_vm() {
  asm volatile("s_waitcnt vmcnt(%0)" :: "i"(N));
}

// async global->LDS, 16B per lane; global src per-lane, LDS dst wave-uniform+lane*16
static __device__ __forceinline__ void gl_lds16(const UST* g, UST* l) {
  __builtin_amdgcn_global_load_lds(
      (const __attribute__((address_space(1))) void*)g,
      (__attribute__((address_space(3))) void*)l, 16, 0, 0);
}

// ======== fused prologue: x cast (blocks 0..4095) + 4x W transpose+cast ========
__global__ __launch_bounds__(256) void k_prologue(const float* __restrict__ x,
                                                  const float* __restrict__ Wq,
                                                  const float* __restrict__ Wk,
                                                  const float* __restrict__ Wv,
                                                  const float* __restrict__ Wo,
                                                  UST* __restrict__ xb,
                                                  UST* __restrict__ wcat,
                                                  UST* __restrict__ wot) {
  int bx = blockIdx.x;
  int tx = threadIdx.x, ty = threadIdx.y;  // 32 x 8
  if (bx < 4096) {  // ---- cast x f32 -> bf16, 8 elems/thread ----
    int tid = ty * 32 + tx;
    size_t i = (size_t)bx * 256 + tid;
    const float4* s4 = reinterpret_cast<const float4*>(x) + 2 * i;
    float4 a = s4[0], b = s4[1];
    union { UST s[8]; uint4 v; } r;
    r.s[0] = f2b(a.x); r.s[1] = f2b(a.y); r.s[2] = f2b(a.z); r.s[3] = f2b(a.w);
    r.s[4] = f2b(b.x); r.s[5] = f2b(b.y); r.s[6] = f2b(b.z); r.s[7] = f2b(b.w);
    reinterpret_cast<uint4*>(xb)[i] = r.v;
    return;
  }
  // ---- transpose+cast: W [2048][N] f32 -> dst [N][2048] bf16 ----
  int u = bx - 4096;
  int ky = u & 63, wsel = u >> 6;
  const float* W; UST* dst; int N; int nb;
  if (wsel < 64)       { W = Wq; dst = wcat;                          N = 2048; nb = wsel; }
  else if (wsel < 80)  { W = Wk; dst = wcat + (size_t)2048 * 2048;    N = 512;  nb = wsel - 64; }
  else if (wsel < 96)  { W = Wv; dst = wcat + (size_t)2560 * 2048;    N = 512;  nb = wsel - 80; }
  else                 { W = Wo; dst = wot;                           N = 2048; nb = wsel - 96; }
  constexpr int K = 2048;
  __shared__ float tile[32][33];
  int nt = nb * 32, kt = ky * 32;
#pragma unroll
  for (int r = 0; r < 4; ++r)
    tile[ty + r * 8][tx] = W[(size_t)(kt + ty + r * 8) * N + nt + tx];
  __syncthreads();
#pragma unroll
  for (int r = 0; r < 4; ++r)
    dst[(size_t)(nt + ty + r * 8) * K + kt + tx] = f2b(tile[tx][ty + r * 8]);
}

// ====== r12 GEMM: slice-granular depth-3 pipeline + r11 swizzle ======
template <int BM, int BN, int WM, int WN, int NMH, int EPI>
__global__ __launch_bounds__(512, 2) void k_gemm2(const UST* __restrict__ A,
                                                  const UST* __restrict__ Bt,
                                                  void* __restrict__ Cv,
                                                  const float* __restrict__ bias,
                                                  int M, int N, int K, int ntn) {
  constexpr int WMR = BM / WM, WNR = BN / WN;
  constexpr int MF = WMR / 16, NF = WNR / 16, MH = MF / NMH;
  constexpr int CA = BM / 128;
  constexpr int CBF = BN / 128;
  constexpr int BREM = (BN % 128) / 64;
  constexpr int AELEMS = 4 * BM * 32;
  __shared__ __align__(16) UST lds[AELEMS + 4 * BN * 32];

  int tid = threadIdx.x, w = tid >> 6, lane = tid & 63;
  int lr = lane & 15, lg = lane >> 4;
  int wm = w / WN, wn = w % WN;

  int q = (int)gridDim.x >> 3;
  int bid = (int)blockIdx.x;
  int swz = (bid & 7) * q + (bid >> 3);
  int mBlk = (swz / ntn) * BM, nBlk = (swz % ntn) * BN;

  v4f acc[MF][NF];
#pragma unroll
  for (int i = 0; i < MF; ++i)
#pragma unroll
    for (int j = 0; j < NF; ++j) acc[i][j] = (v4f){0.f, 0.f, 0.f, 0.f};

  int srow = tid >> 2;
  int scol = ((tid & 3) ^ ((tid >> 3) & 3)) * 8;
  const UST* Abase = A + (size_t)(mBlk + srow) * K + scol;
  const UST* Bbase = Bt + (size_t)(nBlk + srow) * K + scol;
  int ldsW = w * 512;

  auto stageSlice = [&](int v) {
    int reg = v & 3;
    int koff = (v >> 1) * 64 + (v & 1) * 32;
#pragma unroll
    for (int i = 0; i < CA; ++i)
      gl_lds16(Abase + (size_t)(i * 128) * K + koff,
               &lds[reg * BM * 32 + i * 4096 + ldsW]);
#pragma unroll
    for (int i = 0; i < CBF; ++i)
      gl_lds16(Bbase + (size_t)(i * 128) * K + koff,
               &lds[AELEMS + reg * BN * 32 + i * 4096 + ldsW]);
    if constexpr (BREM) {
      if (w < 4)
        gl_lds16(Bbase + (size_t)(CBF * 128) * K + koff,
                 &lds[AELEMS + reg * BN * 32 + CBF * 4096 + ldsW]);
    }
  };
  auto wait2 = [&]() {
    if constexpr (BREM) {
      if (w < 4) wait_vm<2 * (CA + CBF + 1)>();
      else       wait_vm<2 * (CA + CBF)>();
    } else {
      wait_vm<2 * (CA + CBF)>();
    }
  };
  int rslot = ((lg ^ ((lr >> 1) & 3)) * 8);
  auto ldA = [&](int reg, int f) -> v8bf {
    int row = wm * WMR + f * 16 + lr;
    return *(const v8bf*)&lds[(reg * BM + row) * 32 + rslot];
  };
  auto ldB = [&](int reg, int nf) -> v8bf {
    int row = wn * WNR + nf * 16 + lr;
    return *(const v8bf*)&lds[AELEMS + (reg * BN + row) * 32 + rslot];
  };

  int U = K >> 5;
  stageSlice(0); stageSlice(1); stageSlice(2);
  wait2();
  __builtin_amdgcn_s_barrier();

  auto slice = [&](int u, bool issue, int wkind) {
    int reg = u & 3;
    v8bf bfr[NF];
#pragma unroll
    for (int mh = 0; mh < NMH; ++mh) {
      v8bf afr[MH];
      if (mh == 0) {
#pragma unroll
        for (int nf = 0; nf < NF; ++nf) bfr[nf] = ldB(reg, nf);
      }
#pragma unroll
      for (int f = 0; f < MH; ++f) afr[f] = ldA(reg, mh * MH + f);
      if (mh == 0 && issue) stageSlice(u + 3);
      if (mh == NMH - 1) {
        if (wkind == 1) wait2();
        else if (wkind == 2) wait_vm<0>();
      }
      __builtin_amdgcn_s_barrier();
      __builtin_amdgcn_s_setprio(1);
#pragma unroll
      for (int f = 0; f < MH; ++f)
#pragma unroll
        for (int nf = 0; nf < NF; ++nf)
          acc[mh * MH + f][nf] = __builtin_amdgcn_mfma_f32_16x16x32_bf16(
              afr[f], bfr[nf], acc[mh * MH + f][nf], 0, 0, 0);
      __builtin_amdgcn_s_setprio(0);
      __builtin_amdgcn_s_barrier();
    }
  };

  for (int u = 0; u < U - 3; ++u) slice(u, true, 1);
  slice(U - 3, false, 2);
  slice(U - 2, false, 0);
  slice(U - 1, false, 0);

  int row0 = mBlk + wm * WMR + lg * 4;
  int col0 = nBlk + wn * WNR + lr;
#pragma unroll
  for (int fm = 0; fm < MF; ++fm)
#pragma unroll
    for (int nf = 0; nf < NF; ++nf)
#pragma unroll
      for (int r = 0; r < 4; ++r) {
        int row = row0 + fm * 16 + r;
        int col = col0 + nf * 16;
        if constexpr (EPI == 0) {
          ((UST*)Cv)[(size_t)row * N + col] = f2b(acc[fm][nf][r]);
        } else {
          ((float*)Cv)[(size_t)row * N + col] = acc[fm][nf][r] + bias[col];
        }
      }
}

// ======== fused RoPE (blocks 0..2559) + V-transpose (blocks 2560..3071) ========
__global__ __launch_bounds__(256) void k_ropevt(const UST* __restrict__ qkv,
                                                const float* __restrict__ cosT,
                                                const float* __restrict__ sinT,
                                                UST* __restrict__ qh,
                                                UST* __restrict__ kh,
                                                UST* __restrict__ vt) {
  int v = blockIdx.x;
  if (v < 2560) {  // ---- RoPE, 8 d-elems/thread (q pre-scaled 1/8) ----
    int idx = v * 256 + threadIdx.x;
    int q4 = idx & 3;
    int hh = (idx >> 2) % 40;
    int row = idx / 160;            // b*2048 + l
    int l = row & 2047, b = row >> 11;
    int d0 = q4 * 8;
    int col = (hh < 32) ? hh * 64 : 2048 + (hh - 32) * 64;
    const UST* sp = qkv + (size_t)row * 3072 + col + d0;
    union { uint4 v4u; UST u[8]; } t1, t2, o1, o2;
    t1.v4u = *(const uint4*)sp;
    t2.v4u = *(const uint4*)(sp + 32);
    const float4* cp = (const float4*)&cosT[l * 64 + d0];
    const float4* sn = (const float4*)&sinT[l * 64 + d0];
    float4 ca = cp[0], cb = cp[1], sa = sn[0], sb = sn[1];
    float cc[8] = {ca.x, ca.y, ca.z, ca.w, cb.x, cb.y, cb.z, cb.w};
    float ss[8] = {sa.x, sa.y, sa.z, sa.w, sb.x, sb.y, sb.z, sb.w};
    float scale = (hh < 32) ? 0.125f : 1.f;
#pragma unroll
    for (int j = 0; j < 8; ++j) {
      float a = b2f(t1.u[j]), bb = b2f(t2.u[j]);
      o1.u[j] = f2b((a * cc[j] - bb * ss[j]) * scale);
      o2.u[j] = f2b((bb * cc[j] + a * ss[j]) * scale);
    }
    UST* dst = (hh < 32)
        ? qh + (((size_t)b * 32 + hh) * 2048 + l) * 64 + d0
        : kh + (((size_t)b * 8 + (hh - 32)) * 2048 + l) * 64 + d0;
    *(uint4*)dst = o1.v4u;
    *(uint4*)(dst + 32) = o2.v4u;
    return;
  }
  // ---- V transpose: qkv v-slice -> vt [B][8][64][L] ----
  __shared__ __align__(16) UST tl[64][72];
  int u2 = v - 2560;
  int lt = u2 & 31, bg = u2 >> 5;
  int b = bg >> 3, g = bg & 7;
  int t = threadIdx.x;
  int li = t >> 2, d0 = (t & 3) * 16;
  const UST* src = qkv + (size_t)(b * 2048 + lt * 64 + li) * 3072 + 2560 + g * 64 + d0;
  *(uint4*)&tl[li][d0] = *(const uint4*)src;
  *(uint4*)&tl[li][d0 + 8] = *(const uint4*)(src + 8);
  __syncthreads();
  int d = t >> 2, l0 = (t & 3) * 16;
  union { UST u[8]; uint4 v4u; } r0, r1;
#pragma unroll
  for (int e = 0; e < 8; ++e) r0.u[e] = tl[l0 + e][d];
#pragma unroll
  for (int e = 0; e < 8; ++e) r1.u[e] = tl[l0 + 8 + e][d];
  UST* dstp = vt + (size_t)((b * 8 + g) * 64 + d) * 2048 + (size_t)lt * 64 + l0;
  *(uint4*)dstp = r0.v4u;
  *(uint4*)(dstp + 8) = r1.v4u;
}

// ---------------- causal flash attention: balanced pairs (r12, 7x reproduced) ----------------
__global__ __launch_bounds__(512, 4) void k_attn(const UST* __restrict__ qh,
                                                 const UST* __restrict__ kh,
                                                 const UST* __restrict__ vt,
                                                 UST* __restrict__ outp) {
  __shared__ __align__(16) UST k_s[128 * 72];
  __shared__ __align__(16) UST v_s[64 * 136];
  __shared__ __align__(16) UST p_s[8][16 * 136];
  int bx = blockIdx.x, h = blockIdx.y, b = blockIdx.z;
  int g = h >> 2;
  int tid = threadIdx.x, w = tid >> 6, lane = tid & 63;
  int lr = lane & 15, lg = lane >> 4;

  int ksr = tid >> 2, ksc = (tid & 3) * 16;
  int vsr = tid >> 3, vsc = (tid & 7) * 16;
  const UST* kbase = kh + ((size_t)(b * 8 + g) * 2048 + ksr) * 64 + ksc;
  const UST* vbase = vt + ((size_t)(b * 8 + g) * 64 + vsr) * 2048 + vsc;
  UST* kdst = &k_s[ksr * 72 + ksc];
  UST* vdst = &v_s[vsr * 136 + vsc];

  for (int half = 0; half < 2; ++half) {
    int qt = half ? (15 - bx) : bx;
    int qbase = qt * 128 + w * 16;

    const UST* qp = qh + ((size_t)(b * 32 + h) * 2048 + qbase + lr) * 64 + lg * 8;
    v8bf qf0 = *(const v8bf*)qp;
    v8bf qf1 = *(const v8bf*)(qp + 32);

    float m = -1e30f, ls = 0.f;
    v4f o[4];
#pragma unroll
    for (int dt = 0; dt < 4; ++dt) o[dt] = (v4f){0.f, 0.f, 0.f, 0.f};

    __syncthreads();
    uint4 pk0 = *(const uint4*)kbase, pk1 = *(const uint4*)(kbase + 8);
    uint4 pv0 = *(const uint4*)vbase, pv1 = *(const uint4*)(vbase + 8);
    *(uint4*)kdst = pk0; *(uint4*)(kdst + 8) = pk1;
    *(uint4*)vdst = pv0; *(uint4*)(vdst + 8) = pv1;

    for (int j = 0; j <= qt; ++j) {
      __syncthreads();
      bool pref = (j < qt);
      if (pref) {
        const UST* kg = kbase + (size_t)(j + 1) * 8192;
        const UST* vg = vbase + (j + 1) * 128;
        pk0 = *(const uint4*)kg; pk1 = *(const uint4*)(kg + 8);
        pv0 = *(const uint4*)vg; pv1 = *(const uint4*)(vg + 8);
      }

      v4f st[8];
      __builtin_amdgcn_s_setprio(1);
#pragma unroll
      for (int kt = 0; kt < 8; ++kt) {
        const UST* kr = &k_s[(kt * 16 + lr) * 72 + lg * 8];
        v8bf kf0 = *(const v8bf*)kr;
        v8bf kf1 = *(const v8bf*)(kr + 32);
        v4f z = (v4f){0.f, 0.f, 0.f, 0.f};
        z = __builtin_amdgcn_mfma_f32_16x16x32_bf16(kf0, qf0, z, 0, 0, 0);
        z = __builtin_amdgcn_mfma_f32_16x16x32_bf16(kf1, qf1, z, 0, 0, 0);
        st[kt] = z;
      }
      __builtin_amdgcn_s_setprio(0);
      if (j == qt) {
        int qg = qbase + lr;
#pragma unroll
        for (int kt = 0; kt < 8; ++kt)
#pragma unroll
          for (int r = 0; r < 4; ++r) {
            int kg2 = j * 128 + kt * 16 + 4 * lg + r;
            if (kg2 > qg) st[kt][r] = -1e30f;
          }
      }

      float t0 = fmaxf(fmaxf(st[0][0], st[0][1]), fmaxf(st[0][2], st[0][3]));
      float t1 = fmaxf(fmaxf(st[1][0], st[1][1]), fmaxf(st[1][2], st[1][3]));
      float t2 = fmaxf(fmaxf(st[2][0], st[2][1]), fmaxf(st[2][2], st[2][3]));
      float t3 = fmaxf(fmaxf(st[3][0], st[3][1]), fmaxf(st[3][2], st[3][3]));
      float t4 = fmaxf(fmaxf(st[4][0], st[4][1]), fmaxf(st[4][2], st[4][3]));
      float t5 = fmaxf(fmaxf(st[5][0], st[5][1]), fmaxf(st[5][2], st[5][3]));
      float t6 = fmaxf(fmaxf(st[6][0], st[6][1]), fmaxf(st[6][2], st[6][3]));
      float t7 = fmaxf(fmaxf(st[7][0], st[7][1]), fmaxf(st[7][2], st[7][3]));
      float mx = fmaxf(fmaxf(fmaxf(t0, t1), fmaxf(t2, t3)),
                       fmaxf(fmaxf(t4, t5), fmaxf(t6, t7)));
      mx = fmaxf(mx, __shfl_xor(mx, 16));
      mx = fmaxf(mx, __shfl_xor(mx, 32));

      if (!__all(mx <= m + 8.f)) {   // defer-max (T13)
        float mn = fmaxf(m, mx);
        float al = __expf(m - mn);
        m = mn;
        ls *= al;
#pragma unroll
        for (int r = 0; r < 4; ++r) {
          float ar = __shfl(al, 4 * lg + r);
          o[0][r] *= ar; o[1][r] *= ar; o[2][r] *= ar; o[3][r] *= ar;
        }
      }

      constexpr float LOG2E = 1.44269504f;
      float mlog = m * LOG2E;
      float rs = 0.f;
      UST* pw = &p_s[w][lr * 136 + 4 * lg];
#pragma unroll
      for (int kt = 0; kt < 8; ++kt) {
        float p0 = fexp2(__builtin_fmaf(st[kt][0], LOG2E, -mlog));
        float p1 = fexp2(__builtin_fmaf(st[kt][1], LOG2E, -mlog));
        float p2 = fexp2(__builtin_fmaf(st[kt][2], LOG2E, -mlog));
        float p3 = fexp2(__builtin_fmaf(st[kt][3], LOG2E, -mlog));
        rs += (p0 + p1) + (p2 + p3);
        uint2 q2;
        q2.x = cvtpk(p0, p1);
        q2.y = cvtpk(p2, p3);
        *(uint2*)(pw + kt * 16) = q2;
      }

      __builtin_amdgcn_s_setprio(1);
#pragma unroll
      for (int kk = 0; kk < 4; ++kk) {
        v8bf pa = *(const v8bf*)&p_s[w][lr * 136 + kk * 32 + lg * 8];
#pragma unroll
        for (int dt = 0; dt < 4; ++dt) {
          v8bf vb = *(const v8bf*)&v_s[(dt * 16 + lr) * 136 + kk * 32 + lg * 8];
          o[dt] = __builtin_amdgcn_mfma_f32_16x16x32_bf16(pa, vb, o[dt], 0, 0, 0);
        }
      }
      __builtin_amdgcn_s_setprio(0);

      // row-sum reduce AFTER PV (off PV's dependency path)
      rs += __shfl_xor(rs, 16);
      rs += __shfl_xor(rs, 32);
      ls += rs;

      __syncthreads();
      if (pref) {
        *(uint4*)kdst = pk0; *(uint4*)(kdst + 8) = pk1;
        *(uint4*)vdst = pv0; *(uint4*)(vdst + 8) = pv1;
      }
    }

    float iv = 1.f / ls;
#pragma unroll
    for (int r = 0; r < 4; ++r) {
      float ivr = __shfl(iv, 4 * lg + r);
      size_t rowb = ((size_t)b * 2048 + qbase + 4 * lg + r) * 2048 + h * 64 + lr;
#pragma unroll
      for (int dt = 0; dt < 4; ++dt)
        outp[rowb + dt * 16] = f2b(o[dt][r] * ivr);
    }
  }
}

// ---------------- launch ----------------
extern "C" void kernel_launch(void* const* d_in, const int* in_sizes, int n_in,
                              void* d_out, int out_size, void* d_ws, size_t ws_size,
                              hipStream_t stream) {
  const float* x    = (const float*)d_in[0];
  const float* cosT = (const float*)d_in[2];
  const float* sinT = (const float*)d_in[3];
  const float* Wq   = (const float*)d_in[4];
  const float* Wk   = (const float*)d_in[5];
  const float* Wv   = (const float*)d_in[6];
  const float* Wo   = (const float*)d_in[7];
  const float* bo   = (const float*)d_in[8];
  float* out = (float*)d_out;

  char* ws = (char*)d_ws;
  UST* xb   = (UST*)(ws);                       // 16777216 B
  UST* wcat = (UST*)(ws + 16777216);            // 12582912 B
  UST* wot  = (UST*)(ws + 29360128);            //  8388608 B
  UST* qkv  = (UST*)(ws + 37748736);            // 25165824 B
  UST* qhp  = (UST*)(ws + 62914560);            // 16777216 B
  UST* khp  = (UST*)(ws + 79691776);            //  4194304 B
  UST* vtp  = (UST*)(ws + 83886080);            //  4194304 B
  UST* attn_o = xb;  // xb dead after QKV GEMM

  // fused prologue: cast (4096) + 4 transposes (160*64 = 10240) = 14336 blocks
  k_prologue<<<14336, dim3(32, 8), 0, stream>>>(x, Wq, Wk, Wv, Wo, xb, wcat, wot);

  // QKV: 256x192 tiles -> 256 blocks (perfect fill); NMH=1
  k_gemm2<256, 192, 2, 4, 1, 0><<<256, 512, 0, stream>>>(xb, wcat, qkv, nullptr,
                                                         4096, 3072, 2048, 16);
  // fused RoPE (2560) + V transpose (512) = 3072 blocks
  k_ropevt<<<3072, 256, 0, stream>>>(qkv, cosT, sinT, qhp, khp, vtp);

  k_attn<<<dim3(8, 32, 2), 512, 0, stream>>>(qhp, khp, vtp, attn_o);
  // out: 256x128 tiles -> 256 blocks (full fill), NMH=1
  k_gemm2<256, 128, 4, 2, 1, 1><<<256, 512, 0, stream>>>(attn_o, wot, out, bo,
                                                         4096, 2048, 2048, 16);
}